// Round 1
// baseline (311.605 us; speedup 1.0000x reference)
//
#include <hip/hip_runtime.h>

// ---------- types ----------
typedef __bf16 bf16x8 __attribute__((ext_vector_type(8)));
typedef float  f32x4  __attribute__((ext_vector_type(4)));

#define T_SEQ 2048
#define C_DIM 1024
#define NH    16
#define HD    64

__device__ __forceinline__ unsigned short f2bf(float f) {
  unsigned u = __builtin_bit_cast(unsigned, f);
  u += 0x7FFFu + ((u >> 16) & 1u);          // round-to-nearest-even
  return (unsigned short)(u >> 16);
}

__device__ __forceinline__ void gload_lds16(const void* g, void* l) {
  __builtin_amdgcn_global_load_lds(
      (const __attribute__((address_space(1))) unsigned int*)g,
      (__attribute__((address_space(3))) unsigned int*)l, 16, 0, 0);
}

// ---------- prep kernels ----------
__global__ void k_cvt_x(const float* __restrict__ x, unsigned short* __restrict__ xb) {
  const int i = blockIdx.x * 256 + threadIdx.x;   // 1M threads, 4 elems each
  const float4 v = ((const float4*)x)[i];
  ushort4 o;
  o.x = f2bf(v.x); o.y = f2bf(v.y); o.z = f2bf(v.z); o.w = f2bf(v.w);
  ((ushort4*)xb)[i] = o;
}

// Wt[n][k] = bf16(W[k][n])   (1024x1024)
__global__ void k_transpose_w(const float* __restrict__ W, unsigned short* __restrict__ Wt) {
  __shared__ float tile[32][33];
  const int tx = threadIdx.x, ty = threadIdx.y;
  const int n0 = blockIdx.x * 32, k0 = blockIdx.y * 32;
#pragma unroll
  for (int i = 0; i < 32; i += 8)
    tile[ty + i][tx] = W[(size_t)(k0 + ty + i) * C_DIM + n0 + tx];
  __syncthreads();
#pragma unroll
  for (int i = 0; i < 32; i += 8)
    Wt[(size_t)(n0 + ty + i) * C_DIM + k0 + tx] = f2bf(tile[tx][ty + i]);
}

__global__ void k_concat_bias(const float* __restrict__ bq, const float* __restrict__ bk,
                              const float* __restrict__ bv, float* __restrict__ o) {
  const int i = blockIdx.x * 256 + threadIdx.x;   // 3072
  o[i] = (i < 1024) ? bq[i] : (i < 2048 ? bk[i - 1024] : bv[i - 2048]);
}

// ---------- 128x128 bf16 MFMA GEMM mainloop (m97 structure) ----------
// A: [M][K] bf16 row-major.  Bt: [N][K] bf16 row-major (i.e. B transposed).
template<int KDIM>
__device__ __forceinline__ void gemm_tile_mainloop(
    const unsigned short* __restrict__ A,
    const unsigned short* __restrict__ Bt,
    int m0, int n0,
    unsigned short* As, unsigned short* Bs,
    f32x4 acc[4][4])
{
  const int tid  = threadIdx.x;
  const int lane = tid & 63;
  const int wave = tid >> 6;          // 0..3
  const int wr   = wave >> 1, wc = wave & 1;
  const int srow = lane >> 2;         // 0..15
  const int scol = (lane & 3) << 3;   // 0,8,16,24 (elements)
  const int fr   = lane & 15, g = lane >> 4;

  const f32x4 zero = {0.f, 0.f, 0.f, 0.f};
#pragma unroll
  for (int m = 0; m < 4; ++m)
#pragma unroll
    for (int n = 0; n < 4; ++n) acc[m][n] = zero;

  const int nk = KDIM >> 5;
  for (int kt = 0; kt < nk; ++kt) {
    const int kb = kt << 5;
    // stage A-tile [128][32] and B-tile [128][32]; wave handles chunks 2w,2w+1
#pragma unroll
    for (int i = 0; i < 2; ++i) {
      const int c   = wave * 2 + i;           // 0..7
      const int row = c * 16 + srow;
      gload_lds16(A  + (size_t)(m0 + row) * KDIM + kb + scol, As + c * 512);
      gload_lds16(Bt + (size_t)(n0 + row) * KDIM + kb + scol, Bs + c * 512);
    }
    __syncthreads();
    bf16x8 af[4], bfr[4];
    const unsigned short* ap = As + (wr * 64 + fr) * 32 + g * 8;
    const unsigned short* bp = Bs + (wc * 64 + fr) * 32 + g * 8;
#pragma unroll
    for (int m = 0; m < 4; ++m) af[m]  = *(const bf16x8*)(ap + m * 512);
#pragma unroll
    for (int n = 0; n < 4; ++n) bfr[n] = *(const bf16x8*)(bp + n * 512);
#pragma unroll
    for (int m = 0; m < 4; ++m)
#pragma unroll
      for (int n = 0; n < 4; ++n)
        acc[m][n] = __builtin_amdgcn_mfma_f32_16x16x32_bf16(af[m], bfr[n], acc[m][n], 0, 0, 0);
    __syncthreads();
  }
}

// ---------- QKV projection GEMM: X[4096x1024] @ W[1024x3072] ----------
__global__ __launch_bounds__(256) void k_gemm_qkv(
    const unsigned short* __restrict__ Xb,
    const unsigned short* __restrict__ Wt,
    const float* __restrict__ bias,
    unsigned short* __restrict__ Qb,     // [b][h][t][d]  (pre-scaled 1/8)
    unsigned short* __restrict__ Kb,     // [b][h][t][d]
    unsigned short* __restrict__ Vt)     // [b][h][d][t]
{
  __shared__ __attribute__((aligned(16))) unsigned short As[128 * 32];
  __shared__ __attribute__((aligned(16))) unsigned short Bs[128 * 32];
  f32x4 acc[4][4];
  const int m0 = blockIdx.y * 128, n0 = blockIdx.x * 128;
  gemm_tile_mainloop<1024>(Xb, Wt, m0, n0, As, Bs, acc);

  const int lane = threadIdx.x & 63, wave = threadIdx.x >> 6;
  const int wr = wave >> 1, wc = wave & 1;
  const int fr = lane & 15, g = lane >> 4;
  const int j = n0 >> 10;                       // 0=Q 1=K 2=V (tile-uniform)
#pragma unroll
  for (int ni = 0; ni < 4; ++ni) {
    const int col = n0 + wc * 64 + ni * 16 + fr;
    const int c = col & 1023, h = c >> 6, d = c & 63;
    const float bb = bias[col];
#pragma unroll
    for (int mi = 0; mi < 4; ++mi)
#pragma unroll
      for (int r = 0; r < 4; ++r) {
        const int row = m0 + wr * 64 + mi * 16 + g * 4 + r;
        const int b = row >> 11, t = row & 2047;
        const int bh = b * NH + h;
        const float v = acc[mi][ni][r] + bb;
        if (j == 0)      Qb[((size_t)bh * T_SEQ + t) * HD + d] = f2bf(v * 0.125f);
        else if (j == 1) Kb[((size_t)bh * T_SEQ + t) * HD + d] = f2bf(v);
        else             Vt[((size_t)bh * HD + d) * T_SEQ + t] = f2bf(v);
      }
  }
}

// ---------- flash attention: 4 waves/block, 16 q-rows/wave, KBLK=64 ----------
__global__ __launch_bounds__(256) void k_attn(
    const unsigned short* __restrict__ Qb,
    const unsigned short* __restrict__ Kb,
    const unsigned short* __restrict__ Vt,
    unsigned short* __restrict__ Yb)          // [b*T+t][h*64+d]
{
  __shared__ __attribute__((aligned(16))) unsigned short Plds[4][1024]; // 16x64 bf16 per wave
  const int qt   = blockIdx.x;                 // 0..31
  const int bh   = blockIdx.y;                 // 0..31
  const int lane = threadIdx.x & 63;
  const int wave = threadIdx.x >> 6;
  const int fr = lane & 15, g = lane >> 4;
  const int q0 = qt * 64 + wave * 16;
  const size_t hbase = (size_t)bh * T_SEQ * HD;

  const bf16x8 qf0 = *(const bf16x8*)(Qb + hbase + (size_t)(q0 + fr) * HD + g * 8);
  const bf16x8 qf1 = *(const bf16x8*)(Qb + hbase + (size_t)(q0 + fr) * HD + 32 + g * 8);

  const f32x4 zero = {0.f, 0.f, 0.f, 0.f};
  f32x4 yacc[4];
#pragma unroll
  for (int n = 0; n < 4; ++n) yacc[n] = zero;
  float mrow[4] = {-1e30f, -1e30f, -1e30f, -1e30f};
  float lsum[4] = {0.f, 0.f, 0.f, 0.f};

  char* pw = (char*)&Plds[wave][0];

  for (int kkt = 0; kkt <= qt; ++kkt) {
    const int s0 = kkt * 64;
    // S = Q K^T  (Q pre-scaled)
    f32x4 sfr[4];
#pragma unroll
    for (int n = 0; n < 4; ++n) {
      const unsigned short* kp = Kb + hbase + (size_t)(s0 + n * 16 + fr) * HD + g * 8;
      const bf16x8 kf0 = *(const bf16x8*)(kp);
      const bf16x8 kf1 = *(const bf16x8*)(kp + 32);
      f32x4 a = zero;
      a = __builtin_amdgcn_mfma_f32_16x16x32_bf16(qf0, kf0, a, 0, 0, 0);
      a = __builtin_amdgcn_mfma_f32_16x16x32_bf16(qf1, kf1, a, 0, 0, 0);
      sfr[n] = a;
    }
    // mask: s<=t  and  s%4 != 3
    float pmax[4] = {-1e30f, -1e30f, -1e30f, -1e30f};
#pragma unroll
    for (int n = 0; n < 4; ++n) {
      const int sc = s0 + n * 16 + fr;
      const bool colok = ((sc & 3) != 3);
#pragma unroll
      for (int r = 0; r < 4; ++r) {
        const int t = q0 + g * 4 + r;
        const float v = (colok && sc <= t) ? sfr[n][r] : -1e30f;
        sfr[n][r] = v;
        pmax[r] = fmaxf(pmax[r], v);
      }
    }
#pragma unroll
    for (int off = 1; off < 16; off <<= 1)
#pragma unroll
      for (int r = 0; r < 4; ++r)
        pmax[r] = fmaxf(pmax[r], __shfl_xor(pmax[r], off, 64));
#pragma unroll
    for (int r = 0; r < 4; ++r) {
      const float mn = fmaxf(mrow[r], pmax[r]);
      const float corr = __expf(mrow[r] - mn);
      mrow[r] = mn;
      lsum[r] *= corr;
#pragma unroll
      for (int n = 0; n < 4; ++n) yacc[n][r] *= corr;
    }
    __syncthreads();                 // WAR: previous iter's P reads done
    float psum[4] = {0.f, 0.f, 0.f, 0.f};
#pragma unroll
    for (int n = 0; n < 4; ++n)
#pragma unroll
      for (int r = 0; r < 4; ++r) {
        const float p = __expf(sfr[n][r] - mrow[r]);
        psum[r] += p;
        const int prow = g * 4 + r, pcol = n * 16 + fr;
        *(unsigned short*)(pw + prow * 128 + ((pcol * 2) ^ ((prow & 7) << 4))) = f2bf(p);
      }
#pragma unroll
    for (int off = 1; off < 16; off <<= 1)
#pragma unroll
      for (int r = 0; r < 4; ++r)
        psum[r] += __shfl_xor(psum[r], off, 64);
#pragma unroll
    for (int r = 0; r < 4; ++r) lsum[r] += psum[r];
    __syncthreads();                 // RAW: P visible to whole wave
    // Y += P @ V   (V^T rows are contiguous)
#pragma unroll
    for (int kk = 0; kk < 2; ++kk) {
      const bf16x8 pa = *(const bf16x8*)(pw + fr * 128 + (((kk * 32 + g * 8) * 2) ^ ((fr & 7) << 4)));
#pragma unroll
      for (int n = 0; n < 4; ++n) {
        const bf16x8 vf = *(const bf16x8*)(Vt + (size_t)(bh * HD + n * 16 + fr) * T_SEQ + s0 + kk * 32 + g * 8);
        yacc[n] = __builtin_amdgcn_mfma_f32_16x16x32_bf16(pa, vf, yacc[n], 0, 0, 0);
      }
    }
  }
  // epilogue: Y / l  -> Yb row-major [B*T][C]
  const int b = bh >> 4, h = bh & 15;
#pragma unroll
  for (int r = 0; r < 4; ++r) {
    const float inv = 1.0f / lsum[r];
    const int t = q0 + g * 4 + r;
#pragma unroll
    for (int n = 0; n < 4; ++n)
      Yb[((size_t)(b * T_SEQ + t)) * C_DIM + h * HD + n * 16 + fr] = f2bf(yacc[n][r] * inv);
  }
}

// ---------- output projection: Y[4096x1024] @ Wp[1024x1024] + bp -> f32 ----------
__global__ __launch_bounds__(256) void k_gemm_out(
    const unsigned short* __restrict__ Yb,
    const unsigned short* __restrict__ Wpt,
    const float* __restrict__ bp,
    float* __restrict__ out)
{
  __shared__ __attribute__((aligned(16))) unsigned short As[128 * 32];
  __shared__ __attribute__((aligned(16))) unsigned short Bs[128 * 32];
  f32x4 acc[4][4];
  const int m0 = blockIdx.y * 128, n0 = blockIdx.x * 128;
  gemm_tile_mainloop<1024>(Yb, Wpt, m0, n0, As, Bs, acc);

  const int lane = threadIdx.x & 63, wave = threadIdx.x >> 6;
  const int wr = wave >> 1, wc = wave & 1;
  const int fr = lane & 15, g = lane >> 4;
#pragma unroll
  for (int ni = 0; ni < 4; ++ni) {
    const int col = n0 + wc * 64 + ni * 16 + fr;
    const float bb = bp[col];
#pragma unroll
    for (int mi = 0; mi < 4; ++mi)
#pragma unroll
      for (int r = 0; r < 4; ++r) {
        const int row = m0 + wr * 64 + mi * 16 + g * 4 + r;
        out[(size_t)row * C_DIM + col] = acc[mi][ni][r] + bb;
      }
  }
}

// ---------- launch ----------
extern "C" void kernel_launch(void* const* d_in, const int* in_sizes, int n_in,
                              void* d_out, int out_size, void* d_ws, size_t ws_size,
                              hipStream_t stream) {
  const float* x  = (const float*)d_in[0];
  const float* Wq = (const float*)d_in[1];
  const float* bq = (const float*)d_in[2];
  const float* Wk = (const float*)d_in[3];
  const float* bk = (const float*)d_in[4];
  const float* Wv = (const float*)d_in[5];
  const float* bv = (const float*)d_in[6];
  const float* Wp = (const float*)d_in[7];
  const float* bp = (const float*)d_in[8];
  float* out = (float*)d_out;

  char* ws = (char*)d_ws;
  unsigned short* Xb   = (unsigned short*)(ws);                           // 8 MB
  unsigned short* Wt   = (unsigned short*)(ws + (8u  << 20));             // 6 MB [3072][1024]
  unsigned short* Wpt  = (unsigned short*)(ws + (14u << 20));             // 2 MB
  float*          bqkv = (float*)         (ws + (16u << 20));             // 12 KB
  unsigned short* Qb   = (unsigned short*)(ws + (16u << 20) + (64u << 10)); // 8 MB
  unsigned short* Kb   = (unsigned short*)(ws + (24u << 20) + (64u << 10)); // 8 MB
  unsigned short* Vt   = (unsigned short*)(ws + (32u << 20) + (64u << 10)); // 8 MB
  unsigned short* Yb   = (unsigned short*)(ws + (40u << 20) + (64u << 10)); // 8 MB

  k_cvt_x<<<4096, 256, 0, stream>>>(x, Xb);
  dim3 tb(32, 8);
  k_transpose_w<<<dim3(32, 32), tb, 0, stream>>>(Wq, Wt);
  k_transpose_w<<<dim3(32, 32), tb, 0, stream>>>(Wk, Wt + (1u << 20));
  k_transpose_w<<<dim3(32, 32), tb, 0, stream>>>(Wv, Wt + (2u << 20));
  k_transpose_w<<<dim3(32, 32), tb, 0, stream>>>(Wp, Wpt);
  k_concat_bias<<<12, 256, 0, stream>>>(bq, bk, bv, bqkv);
  k_gemm_qkv<<<dim3(24, 32), 256, 0, stream>>>(Xb, Wt, bqkv, Qb, Kb, Vt);
  k_attn<<<dim3(32, 32), 256, 0, stream>>>(Qb, Kb, Vt, Yb);
  k_gemm_out<<<dim3(8, 32), 256, 0, stream>>>(Yb, Wpt, bp, out);
}

// Round 2
// 260.707 us; speedup vs baseline: 1.1952x; 1.1952x over previous
//
#include <hip/hip_runtime.h>

// ---------- types ----------
typedef __bf16 bf16x8 __attribute__((ext_vector_type(8)));
typedef float  f32x4  __attribute__((ext_vector_type(4)));

#define T_SEQ 2048
#define C_DIM 1024
#define NH    16
#define HD    64

__device__ __forceinline__ unsigned short f2bf(float f) {
  unsigned u = __builtin_bit_cast(unsigned, f);
  u += 0x7FFFu + ((u >> 16) & 1u);          // round-to-nearest-even
  return (unsigned short)(u >> 16);
}

__device__ __forceinline__ void gload_lds16(const void* g, void* l) {
  __builtin_amdgcn_global_load_lds(
      (const __attribute__((address_space(1))) unsigned int*)g,
      (__attribute__((address_space(3))) unsigned int*)l, 16, 0, 0);
}

// ---------- prep kernels ----------
__global__ void k_cvt_x(const float* __restrict__ x, unsigned short* __restrict__ xb) {
  const int i = blockIdx.x * 256 + threadIdx.x;   // 1M threads, 4 elems each
  const float4 v = ((const float4*)x)[i];
  ushort4 o;
  o.x = f2bf(v.x); o.y = f2bf(v.y); o.z = f2bf(v.z); o.w = f2bf(v.w);
  ((ushort4*)xb)[i] = o;
}

// Wt[n][k] = bf16(W[k][n])   (1024x1024)
__global__ void k_transpose_w(const float* __restrict__ W, unsigned short* __restrict__ Wt) {
  __shared__ float tile[32][33];
  const int tx = threadIdx.x, ty = threadIdx.y;
  const int n0 = blockIdx.x * 32, k0 = blockIdx.y * 32;
#pragma unroll
  for (int i = 0; i < 32; i += 8)
    tile[ty + i][tx] = W[(size_t)(k0 + ty + i) * C_DIM + n0 + tx];
  __syncthreads();
#pragma unroll
  for (int i = 0; i < 32; i += 8)
    Wt[(size_t)(n0 + ty + i) * C_DIM + k0 + tx] = f2bf(tile[tx][ty + i]);
}

__global__ void k_concat_bias(const float* __restrict__ bq, const float* __restrict__ bk,
                              const float* __restrict__ bv, float* __restrict__ o) {
  const int i = blockIdx.x * 256 + threadIdx.x;   // 3072
  o[i] = (i < 1024) ? bq[i] : (i < 2048 ? bk[i - 1024] : bv[i - 2048]);
}

// ---------- 128x128 bf16 MFMA GEMM mainloop (m97 structure) ----------
template<int KDIM>
__device__ __forceinline__ void gemm_tile_mainloop(
    const unsigned short* __restrict__ A,
    const unsigned short* __restrict__ Bt,
    int m0, int n0,
    unsigned short* As, unsigned short* Bs,
    f32x4 acc[4][4])
{
  const int tid  = threadIdx.x;
  const int lane = tid & 63;
  const int wave = tid >> 6;          // 0..3
  const int wr   = wave >> 1, wc = wave & 1;
  const int srow = lane >> 2;         // 0..15
  const int scol = (lane & 3) << 3;   // 0,8,16,24 (elements)
  const int fr   = lane & 15, g = lane >> 4;

  const f32x4 zero = {0.f, 0.f, 0.f, 0.f};
#pragma unroll
  for (int m = 0; m < 4; ++m)
#pragma unroll
    for (int n = 0; n < 4; ++n) acc[m][n] = zero;

  const int nk = KDIM >> 5;
  for (int kt = 0; kt < nk; ++kt) {
    const int kb = kt << 5;
#pragma unroll
    for (int i = 0; i < 2; ++i) {
      const int c   = wave * 2 + i;           // 0..7
      const int row = c * 16 + srow;
      gload_lds16(A  + (size_t)(m0 + row) * KDIM + kb + scol, As + c * 512);
      gload_lds16(Bt + (size_t)(n0 + row) * KDIM + kb + scol, Bs + c * 512);
    }
    __syncthreads();
    bf16x8 af[4], bfr[4];
    const unsigned short* ap = As + (wr * 64 + fr) * 32 + g * 8;
    const unsigned short* bp = Bs + (wc * 64 + fr) * 32 + g * 8;
#pragma unroll
    for (int m = 0; m < 4; ++m) af[m]  = *(const bf16x8*)(ap + m * 512);
#pragma unroll
    for (int n = 0; n < 4; ++n) bfr[n] = *(const bf16x8*)(bp + n * 512);
#pragma unroll
    for (int m = 0; m < 4; ++m)
#pragma unroll
      for (int n = 0; n < 4; ++n)
        acc[m][n] = __builtin_amdgcn_mfma_f32_16x16x32_bf16(af[m], bfr[n], acc[m][n], 0, 0, 0);
    __syncthreads();
  }
}

// ---------- QKV projection GEMM ----------
__global__ __launch_bounds__(256) void k_gemm_qkv(
    const unsigned short* __restrict__ Xb,
    const unsigned short* __restrict__ Wt,
    const float* __restrict__ bias,
    unsigned short* __restrict__ Qb,     // [b][h][t][d]  (pre-scaled 1/8)
    unsigned short* __restrict__ Kb,     // [b][h][t][d]
    unsigned short* __restrict__ Vt)     // [b][h][d][t]
{
  __shared__ __attribute__((aligned(16))) unsigned short As[128 * 32];
  __shared__ __attribute__((aligned(16))) unsigned short Bs[128 * 32];
  f32x4 acc[4][4];
  const int m0 = blockIdx.y * 128, n0 = blockIdx.x * 128;
  gemm_tile_mainloop<1024>(Xb, Wt, m0, n0, As, Bs, acc);

  const int lane = threadIdx.x & 63, wave = threadIdx.x >> 6;
  const int wr = wave >> 1, wc = wave & 1;
  const int fr = lane & 15, g = lane >> 4;
  const int j = n0 >> 10;                       // 0=Q 1=K 2=V
#pragma unroll
  for (int ni = 0; ni < 4; ++ni) {
    const int col = n0 + wc * 64 + ni * 16 + fr;
    const int c = col & 1023, h = c >> 6, d = c & 63;
    const float bb = bias[col];
#pragma unroll
    for (int mi = 0; mi < 4; ++mi)
#pragma unroll
      for (int r = 0; r < 4; ++r) {
        const int row = m0 + wr * 64 + mi * 16 + g * 4 + r;
        const int b = row >> 11, t = row & 2047;
        const int bh = b * NH + h;
        const float v = acc[mi][ni][r] + bb;
        if (j == 0)      Qb[((size_t)bh * T_SEQ + t) * HD + d] = f2bf(v * 0.125f);
        else if (j == 1) Kb[((size_t)bh * T_SEQ + t) * HD + d] = f2bf(v);
        else             Vt[((size_t)bh * HD + d) * T_SEQ + t] = f2bf(v);
      }
  }
}

// ---------- flash attention: 1 wave/block, 16 q-rows, KBLK=64, K prefetch ----------
__global__ __launch_bounds__(64) void k_attn(
    const unsigned short* __restrict__ Qb,
    const unsigned short* __restrict__ Kb,
    const unsigned short* __restrict__ Vt,
    unsigned short* __restrict__ Yb)          // [b*T+t][h*64+d]
{
  __shared__ __attribute__((aligned(16))) unsigned short Plds[1024]; // 16x64 bf16
  const int qt   = 127 - blockIdx.x;           // heavy-first dispatch
  const int bh   = blockIdx.y;                 // 0..31
  const int lane = threadIdx.x & 63;
  const int fr = lane & 15, g = lane >> 4;
  const int q0 = qt * 16;
  const size_t hbase = (size_t)bh * T_SEQ * HD;
  const size_t vbase = (size_t)bh * HD * T_SEQ;

  const bf16x8 qf0 = *(const bf16x8*)(Qb + hbase + (size_t)(q0 + fr) * HD + g * 8);
  const bf16x8 qf1 = *(const bf16x8*)(Qb + hbase + (size_t)(q0 + fr) * HD + 32 + g * 8);

  const f32x4 zero = {0.f, 0.f, 0.f, 0.f};
  f32x4 yacc[4];
#pragma unroll
  for (int n = 0; n < 4; ++n) yacc[n] = zero;
  float mrow[4] = {-1e30f, -1e30f, -1e30f, -1e30f};
  float lsum[4] = {0.f, 0.f, 0.f, 0.f};
  const float colmul = ((fr & 3) != 3) ? 1.0f : 0.0f;   // column mask (s%4==3 -> 0)
  char* pw = (char*)Plds;
  const int ndiag = qt >> 2;                   // tile index of diagonal tile

  bf16x8 kA[4][2], kB[4][2];

  auto LOADK = [&](bf16x8 (&kf)[4][2], int s0) {
#pragma unroll
    for (int n = 0; n < 4; ++n) {
      const unsigned short* kp = Kb + hbase + (size_t)(s0 + n * 16 + fr) * HD + g * 8;
      kf[n][0] = *(const bf16x8*)(kp);
      kf[n][1] = *(const bf16x8*)(kp + 32);
    }
  };

  auto BODY = [&](bf16x8 (&kf)[4][2], int s0, bool diag) {
    // S = Q K^T  (Q pre-scaled by 1/8)
    f32x4 sfr[4];
#pragma unroll
    for (int n = 0; n < 4; ++n) {
      f32x4 a = zero;
      a = __builtin_amdgcn_mfma_f32_16x16x32_bf16(qf0, kf[n][0], a, 0, 0, 0);
      a = __builtin_amdgcn_mfma_f32_16x16x32_bf16(qf1, kf[n][1], a, 0, 0, 0);
      sfr[n] = a;
    }
    float pmax[4] = {-1e30f, -1e30f, -1e30f, -1e30f};
    if (diag) {
      const bool colok = (fr & 3) != 3;
#pragma unroll
      for (int n = 0; n < 4; ++n) {
        const int sc = s0 + n * 16 + fr;
#pragma unroll
        for (int r = 0; r < 4; ++r) {
          const int t = q0 + g * 4 + r;
          const float v = (colok && sc <= t) ? sfr[n][r] : -1e30f;
          sfr[n][r] = v;
          pmax[r] = fmaxf(pmax[r], v);
        }
      }
    } else {
      // interior: include col-masked entries in max (exact: m overestimate
      // rescales numerator and denominator identically); zero them at p.
#pragma unroll
      for (int n = 0; n < 4; ++n)
#pragma unroll
        for (int r = 0; r < 4; ++r) pmax[r] = fmaxf(pmax[r], sfr[n][r]);
    }
#pragma unroll
    for (int off = 1; off < 16; off <<= 1)
#pragma unroll
      for (int r = 0; r < 4; ++r)
        pmax[r] = fmaxf(pmax[r], __shfl_xor(pmax[r], off, 64));
#pragma unroll
    for (int r = 0; r < 4; ++r) {
      const float mn = fmaxf(mrow[r], pmax[r]);
      const float corr = __expf(mrow[r] - mn);
      mrow[r] = mn;
      lsum[r] *= corr;
#pragma unroll
      for (int n = 0; n < 4; ++n) yacc[n][r] *= corr;
    }
    float psum[4] = {0.f, 0.f, 0.f, 0.f};
#pragma unroll
    for (int n = 0; n < 4; ++n)
#pragma unroll
      for (int r = 0; r < 4; ++r) {
        float p = __expf(sfr[n][r] - mrow[r]);
        if (!diag) p *= colmul;               // zero masked columns
        psum[r] += p;
        const int prow = g * 4 + r, pcol = n * 16 + fr;
        *(unsigned short*)(pw + prow * 128 + ((pcol * 2) ^ ((prow & 7) << 4))) = f2bf(p);
      }
    // Y += P @ V   (in-order DS pipe: reads wait for this wave's writes)
#pragma unroll
    for (int kk = 0; kk < 2; ++kk) {
      const bf16x8 pa = *(const bf16x8*)(pw + fr * 128 + (((kk * 32 + g * 8) * 2) ^ ((fr & 7) << 4)));
#pragma unroll
      for (int n = 0; n < 4; ++n) {
        const bf16x8 vf = *(const bf16x8*)(Vt + vbase + (size_t)(n * 16 + fr) * T_SEQ + s0 + kk * 32 + g * 8);
        yacc[n] = __builtin_amdgcn_mfma_f32_16x16x32_bf16(pa, vf, yacc[n], 0, 0, 0);
      }
    }
    // lsum tree off the critical path (after PV issue)
#pragma unroll
    for (int off = 1; off < 16; off <<= 1)
#pragma unroll
      for (int r = 0; r < 4; ++r)
        psum[r] += __shfl_xor(psum[r], off, 64);
#pragma unroll
    for (int r = 0; r < 4; ++r) lsum[r] += psum[r];
  };

  // ping-pong over s-tiles 0..ndiag with K register prefetch
  LOADK(kA, 0);
  int i = 0;
  for (;;) {
    if (i + 1 <= ndiag) LOADK(kB, (i + 1) * 64);
    BODY(kA, i * 64, i == ndiag);
    if (++i > ndiag) break;
    if (i + 1 <= ndiag) LOADK(kA, (i + 1) * 64);
    BODY(kB, i * 64, i == ndiag);
    if (++i > ndiag) break;
  }

  // epilogue
  const int b = bh >> 4, h = bh & 15;
#pragma unroll
  for (int r = 0; r < 4; ++r) {
    const float inv = 1.0f / lsum[r];
    const int t = q0 + g * 4 + r;
#pragma unroll
    for (int n = 0; n < 4; ++n)
      Yb[((size_t)(b * T_SEQ + t)) * C_DIM + h * HD + n * 16 + fr] = f2bf(yacc[n][r] * inv);
  }
}

// ---------- output projection ----------
__global__ __launch_bounds__(256) void k_gemm_out(
    const unsigned short* __restrict__ Yb,
    const unsigned short* __restrict__ Wpt,
    const float* __restrict__ bp,
    float* __restrict__ out)
{
  __shared__ __attribute__((aligned(16))) unsigned short As[128 * 32];
  __shared__ __attribute__((aligned(16))) unsigned short Bs[128 * 32];
  f32x4 acc[4][4];
  const int m0 = blockIdx.y * 128, n0 = blockIdx.x * 128;
  gemm_tile_mainloop<1024>(Yb, Wpt, m0, n0, As, Bs, acc);

  const int lane = threadIdx.x & 63, wave = threadIdx.x >> 6;
  const int wr = wave >> 1, wc = wave & 1;
  const int fr = lane & 15, g = lane >> 4;
#pragma unroll
  for (int ni = 0; ni < 4; ++ni) {
    const int col = n0 + wc * 64 + ni * 16 + fr;
    const float bb = bp[col];
#pragma unroll
    for (int mi = 0; mi < 4; ++mi)
#pragma unroll
      for (int r = 0; r < 4; ++r) {
        const int row = m0 + wr * 64 + mi * 16 + g * 4 + r;
        out[(size_t)row * C_DIM + col] = acc[mi][ni][r] + bb;
      }
  }
}

// ---------- launch ----------
extern "C" void kernel_launch(void* const* d_in, const int* in_sizes, int n_in,
                              void* d_out, int out_size, void* d_ws, size_t ws_size,
                              hipStream_t stream) {
  const float* x  = (const float*)d_in[0];
  const float* Wq = (const float*)d_in[1];
  const float* bq = (const float*)d_in[2];
  const float* Wk = (const float*)d_in[3];
  const float* bk = (const float*)d_in[4];
  const float* Wv = (const float*)d_in[5];
  const float* bv = (const float*)d_in[6];
  const float* Wp = (const float*)d_in[7];
  const float* bp = (const float*)d_in[8];
  float* out = (float*)d_out;

  char* ws = (char*)d_ws;
  unsigned short* Xb   = (unsigned short*)(ws);                             // 8 MB
  unsigned short* Wt   = (unsigned short*)(ws + (8u  << 20));               // 6 MB
  unsigned short* Wpt  = (unsigned short*)(ws + (14u << 20));               // 2 MB
  float*          bqkv = (float*)         (ws + (16u << 20));               // 12 KB
  unsigned short* Qb   = (unsigned short*)(ws + (16u << 20) + (64u << 10)); // 8 MB
  unsigned short* Kb   = (unsigned short*)(ws + (24u << 20) + (64u << 10)); // 8 MB
  unsigned short* Vt   = (unsigned short*)(ws + (32u << 20) + (64u << 10)); // 8 MB
  unsigned short* Yb   = (unsigned short*)(ws + (40u << 20) + (64u << 10)); // 8 MB

  k_cvt_x<<<4096, 256, 0, stream>>>(x, Xb);
  dim3 tb(32, 8);
  k_transpose_w<<<dim3(32, 32), tb, 0, stream>>>(Wq, Wt);
  k_transpose_w<<<dim3(32, 32), tb, 0, stream>>>(Wk, Wt + (1u << 20));
  k_transpose_w<<<dim3(32, 32), tb, 0, stream>>>(Wv, Wt + (2u << 20));
  k_transpose_w<<<dim3(32, 32), tb, 0, stream>>>(Wp, Wpt);
  k_concat_bias<<<12, 256, 0, stream>>>(bq, bk, bv, bqkv);
  k_gemm_qkv<<<dim3(24, 32), 256, 0, stream>>>(Xb, Wt, bqkv, Qb, Kb, Vt);
  k_attn<<<dim3(128, 32), 64, 0, stream>>>(Qb, Kb, Vt, Yb);
  k_gemm_out<<<dim3(8, 32), 256, 0, stream>>>(Yb, Wpt, bp, out);
}

// Round 4
// 217.831 us; speedup vs baseline: 1.4305x; 1.1968x over previous
//
#include <hip/hip_runtime.h>

// ---------- types ----------
typedef __bf16 bf16x8 __attribute__((ext_vector_type(8)));
typedef float  f32x4  __attribute__((ext_vector_type(4)));
typedef unsigned int u32x2 __attribute__((ext_vector_type(2)));
typedef __attribute__((address_space(3))) const unsigned short* lds_cp;

#define T_SEQ 2048
#define C_DIM 1024
#define NH    16
#define HD    64
#define LOG2E 1.4426950408889634f

__device__ __forceinline__ unsigned short f2bf(float f) {
  unsigned u = __builtin_bit_cast(unsigned, f);
  u += 0x7FFFu + ((u >> 16) & 1u);          // round-to-nearest-even
  return (unsigned short)(u >> 16);
}

__device__ __forceinline__ unsigned cvtpk(float lo, float hi) {
  unsigned r;
  asm("v_cvt_pk_bf16_f32 %0, %1, %2" : "=v"(r) : "v"(lo), "v"(hi));
  return r;
}

// HW transpose read. Lane p of each 16-lane group must supply
// addr = group_base + p*8 BYTES (its own 64-bit word of the 128B block);
// the fixed transpose network then delivers elem j = group_base_elem + p + j*16.
__device__ __forceinline__ bf16x8 tr_frag(lds_cp addr) {
  u32x2 lo, hi;
  asm volatile("ds_read_b64_tr_b16 %0, %2 offset:0\n\t"
               "ds_read_b64_tr_b16 %1, %2 offset:128"
               : "=&v"(lo), "=&v"(hi) : "v"(addr) : "memory");
  struct { u32x2 a, b; } s{lo, hi};
  return __builtin_bit_cast(bf16x8, s);
}

__device__ __forceinline__ void gload_lds16(const void* g, void* l) {
  __builtin_amdgcn_global_load_lds(
      (const __attribute__((address_space(1))) unsigned int*)g,
      (__attribute__((address_space(3))) unsigned int*)l, 16, 0, 0);
}

// ---------- prep kernels ----------
__global__ void k_cvt_x(const float* __restrict__ x, unsigned short* __restrict__ xb) {
  const int i = blockIdx.x * 256 + threadIdx.x;
  const float4 v = ((const float4*)x)[i];
  ushort4 o;
  o.x = f2bf(v.x); o.y = f2bf(v.y); o.z = f2bf(v.z); o.w = f2bf(v.w);
  ((ushort4*)xb)[i] = o;
}

__global__ void k_transpose_w(const float* __restrict__ W, unsigned short* __restrict__ Wt) {
  __shared__ float tile[32][33];
  const int tx = threadIdx.x, ty = threadIdx.y;
  const int n0 = blockIdx.x * 32, k0 = blockIdx.y * 32;
#pragma unroll
  for (int i = 0; i < 32; i += 8)
    tile[ty + i][tx] = W[(size_t)(k0 + ty + i) * C_DIM + n0 + tx];
  __syncthreads();
#pragma unroll
  for (int i = 0; i < 32; i += 8)
    Wt[(size_t)(n0 + ty + i) * C_DIM + k0 + tx] = f2bf(tile[tx][ty + i]);
}

__global__ void k_concat_bias(const float* __restrict__ bq, const float* __restrict__ bk,
                              const float* __restrict__ bv, float* __restrict__ o) {
  const int i = blockIdx.x * 256 + threadIdx.x;
  o[i] = (i < 1024) ? bq[i] : (i < 2048 ? bk[i - 1024] : bv[i - 2048]);
}

// ---------- 128x128 bf16 MFMA GEMM mainloop ----------
template<int KDIM>
__device__ __forceinline__ void gemm_tile_mainloop(
    const unsigned short* __restrict__ A,
    const unsigned short* __restrict__ Bt,
    int m0, int n0,
    unsigned short* As, unsigned short* Bs,
    f32x4 acc[4][4])
{
  const int tid  = threadIdx.x;
  const int lane = tid & 63;
  const int wave = tid >> 6;
  const int wr   = wave >> 1, wc = wave & 1;
  const int srow = lane >> 2;
  const int scol = (lane & 3) << 3;
  const int fr   = lane & 15, g = lane >> 4;

  const f32x4 zero = {0.f, 0.f, 0.f, 0.f};
#pragma unroll
  for (int m = 0; m < 4; ++m)
#pragma unroll
    for (int n = 0; n < 4; ++n) acc[m][n] = zero;

  const int nk = KDIM >> 5;
  for (int kt = 0; kt < nk; ++kt) {
    const int kb = kt << 5;
#pragma unroll
    for (int i = 0; i < 2; ++i) {
      const int c   = wave * 2 + i;
      const int row = c * 16 + srow;
      gload_lds16(A  + (size_t)(m0 + row) * KDIM + kb + scol, As + c * 512);
      gload_lds16(Bt + (size_t)(n0 + row) * KDIM + kb + scol, Bs + c * 512);
    }
    __syncthreads();
    bf16x8 af[4], bfr[4];
    const unsigned short* ap = As + (wr * 64 + fr) * 32 + g * 8;
    const unsigned short* bp = Bs + (wc * 64 + fr) * 32 + g * 8;
#pragma unroll
    for (int m = 0; m < 4; ++m) af[m]  = *(const bf16x8*)(ap + m * 512);
#pragma unroll
    for (int n = 0; n < 4; ++n) bfr[n] = *(const bf16x8*)(bp + n * 512);
#pragma unroll
    for (int m = 0; m < 4; ++m)
#pragma unroll
      for (int n = 0; n < 4; ++n)
        acc[m][n] = __builtin_amdgcn_mfma_f32_16x16x32_bf16(af[m], bfr[n], acc[m][n], 0, 0, 0);
    __syncthreads();
  }
}

// ---------- QKV projection GEMM ----------
__global__ __launch_bounds__(256) void k_gemm_qkv(
    const unsigned short* __restrict__ Xb,
    const unsigned short* __restrict__ Wt,
    const float* __restrict__ bias,
    unsigned short* __restrict__ Qb,     // [b][h][t][d]  (pre-scaled 0.125*log2e)
    unsigned short* __restrict__ Kb,     // [b][h][t][d]
    unsigned short* __restrict__ Vt)     // [b][h][d][t]
{
  __shared__ __attribute__((aligned(16))) unsigned short As[128 * 32];
  __shared__ __attribute__((aligned(16))) unsigned short Bs[128 * 32];
  f32x4 acc[4][4];
  const int m0 = blockIdx.y * 128, n0 = blockIdx.x * 128;
  gemm_tile_mainloop<1024>(Xb, Wt, m0, n0, As, Bs, acc);

  const int lane = threadIdx.x & 63, wave = threadIdx.x >> 6;
  const int wr = wave >> 1, wc = wave & 1;
  const int fr = lane & 15, g = lane >> 4;
  const int j = n0 >> 10;
#pragma unroll
  for (int ni = 0; ni < 4; ++ni) {
    const int col = n0 + wc * 64 + ni * 16 + fr;
    const int c = col & 1023, h = c >> 6, d = c & 63;
    const float bb = bias[col];
#pragma unroll
    for (int mi = 0; mi < 4; ++mi)
#pragma unroll
      for (int r = 0; r < 4; ++r) {
        const int row = m0 + wr * 64 + mi * 16 + g * 4 + r;
        const int b = row >> 11, t = row & 2047;
        const int bh = b * NH + h;
        const float v = acc[mi][ni][r] + bb;
        if (j == 0)      Qb[((size_t)bh * T_SEQ + t) * HD + d] = f2bf(v * (0.125f * LOG2E));
        else if (j == 1) Kb[((size_t)bh * T_SEQ + t) * HD + d] = f2bf(v);
        else             Vt[((size_t)bh * HD + d) * T_SEQ + t] = f2bf(v);
      }
  }
}

// ---------- flash attention: 1 wave/block, 2x16 q-rows, KBLK=64 ----------
__global__ __launch_bounds__(64) void k_attn(
    const unsigned short* __restrict__ Qb,
    const unsigned short* __restrict__ Kb,
    const unsigned short* __restrict__ Vt,
    unsigned short* __restrict__ Yb)
{
  __shared__ __attribute__((aligned(128))) unsigned short Pc[2][64][16]; // [s][q] col-major P
  const int qt   = 63 - blockIdx.x;            // 32-row q-block, heavy-first
  const int bh   = blockIdx.y;
  const int lane = threadIdx.x & 63;
  const int fr = lane & 15, g = lane >> 4;
  const int q0 = qt * 32;
  const size_t hbase = (size_t)bh * T_SEQ * HD;
  const unsigned short* Kh = Kb + hbase;
  const unsigned short* Vh = Vt + (size_t)bh * HD * T_SEQ;

  const unsigned short* qp = Qb + hbase + (size_t)(q0 + fr) * HD + g * 8;
  const bf16x8 qA0 = *(const bf16x8*)(qp);
  const bf16x8 qA1 = *(const bf16x8*)(qp + 32);
  const bf16x8 qB0 = *(const bf16x8*)(qp + 16 * HD);
  const bf16x8 qB1 = *(const bf16x8*)(qp + 16 * HD + 32);

  const f32x4 zero = {0.f, 0.f, 0.f, 0.f};
  f32x4 yA[4], yB[4];
#pragma unroll
  for (int n = 0; n < 4; ++n) { yA[n] = zero; yB[n] = zero; }
  float mA[4], mB[4], lA[4], lB[4];
#pragma unroll
  for (int r = 0; r < 4; ++r) { mA[r] = -1e30f; mB[r] = -1e30f; lA[r] = 0.f; lB[r] = 0.f; }
  const float colmul = ((fr & 3) != 3) ? 1.0f : 0.0f;
  const int ndiag = qt >> 1;

  char* pwA = (char*)&Pc[0][0][0] + fr * 32 + g * 8;   // +n*512 per 16-s chunk
  char* pwB = (char*)&Pc[1][0][0] + fr * 32 + g * 8;
  // tr-read base: lane p of 16-lane group points at its OWN 8-byte word:
  // byte addr = fr*8 + g*256  (element addr = fr*4 + g*128)
  lds_cp trA = (lds_cp)(const unsigned short*)&Pc[0][0][0] + fr * 4 + g * 128; // +512 elems for kk=1
  lds_cp trB = (lds_cp)(const unsigned short*)&Pc[1][0][0] + fr * 4 + g * 128;

  bf16x8 k0[4][2], k1[4][2];

  auto LOADK = [&](bf16x8 (&kf)[4][2], int s0) {
#pragma unroll
    for (int n = 0; n < 4; ++n) {
      const unsigned short* kp = Kh + (size_t)(s0 + n * 16 + fr) * HD + g * 8;
      kf[n][0] = *(const bf16x8*)(kp);
      kf[n][1] = *(const bf16x8*)(kp + 32);
    }
  };

  auto BODY = [&](const bf16x8 (&kf)[4][2], int s0, bool diag) {
    // ---- QK^T for both sub-tiles (S already in log2 domain) ----
    f32x4 sA[4], sB[4];
#pragma unroll
    for (int n = 0; n < 4; ++n) {
      f32x4 a = zero, b = zero;
      a = __builtin_amdgcn_mfma_f32_16x16x32_bf16(qA0, kf[n][0], a, 0, 0, 0);
      a = __builtin_amdgcn_mfma_f32_16x16x32_bf16(qA1, kf[n][1], a, 0, 0, 0);
      b = __builtin_amdgcn_mfma_f32_16x16x32_bf16(qB0, kf[n][0], b, 0, 0, 0);
      b = __builtin_amdgcn_mfma_f32_16x16x32_bf16(qB1, kf[n][1], b, 0, 0, 0);
      sA[n] = a; sB[n] = b;
    }
    // ---- masks + per-row tile max ----
    float pmA[4], pmB[4];
#pragma unroll
    for (int r = 0; r < 4; ++r) { pmA[r] = -1e30f; pmB[r] = -1e30f; }
    if (diag) {
      const bool colok = (fr & 3) != 3;
#pragma unroll
      for (int n = 0; n < 4; ++n) {
        const int sc = s0 + n * 16 + fr;
#pragma unroll
        for (int r = 0; r < 4; ++r) {
          const int tA = q0 + g * 4 + r;
          float v = (colok && sc <= tA) ? sA[n][r] : -1e30f;
          sA[n][r] = v; pmA[r] = fmaxf(pmA[r], v);
          v = (colok && sc <= tA + 16) ? sB[n][r] : -1e30f;
          sB[n][r] = v; pmB[r] = fmaxf(pmB[r], v);
        }
      }
    } else {
      // interior: masked cols included in max (exact), zeroed after exp2
#pragma unroll
      for (int n = 0; n < 4; ++n)
#pragma unroll
        for (int r = 0; r < 4; ++r) {
          pmA[r] = fmaxf(pmA[r], sA[n][r]);
          pmB[r] = fmaxf(pmB[r], sB[n][r]);
        }
    }
#pragma unroll
    for (int off = 1; off < 16; off <<= 1)
#pragma unroll
      for (int r = 0; r < 4; ++r) {
        pmA[r] = fmaxf(pmA[r], __shfl_xor(pmA[r], off, 64));
        pmB[r] = fmaxf(pmB[r], __shfl_xor(pmB[r], off, 64));
      }
    // ---- defer-max (THR=8 in log2 domain) ----
    const float needA = fmaxf(fmaxf(pmA[0] - mA[0], pmA[1] - mA[1]),
                              fmaxf(pmA[2] - mA[2], pmA[3] - mA[3]));
    if (__any(needA > 8.0f)) {
#pragma unroll
      for (int r = 0; r < 4; ++r) {
        const float mn = fmaxf(mA[r], pmA[r]);
        const float corr = exp2f(mA[r] - mn);
        mA[r] = mn; lA[r] *= corr;
#pragma unroll
        for (int n = 0; n < 4; ++n) yA[n][r] *= corr;
      }
    }
    const float needB = fmaxf(fmaxf(pmB[0] - mB[0], pmB[1] - mB[1]),
                              fmaxf(pmB[2] - mB[2], pmB[3] - mB[3]));
    if (__any(needB > 8.0f)) {
#pragma unroll
      for (int r = 0; r < 4; ++r) {
        const float mn = fmaxf(mB[r], pmB[r]);
        const float corr = exp2f(mB[r] - mn);
        mB[r] = mn; lB[r] *= corr;
#pragma unroll
        for (int n = 0; n < 4; ++n) yB[n][r] *= corr;
      }
    }
    // ---- V loads early (latency overlap with softmax tail) ----
    bf16x8 vf[4][2];
#pragma unroll
    for (int n = 0; n < 4; ++n)
#pragma unroll
      for (int kk = 0; kk < 2; ++kk)
        vf[n][kk] = *(const bf16x8*)(Vh + (size_t)(n * 16 + fr) * T_SEQ + s0 + kk * 32 + g * 8);
    // ---- p = exp2(s-m), pack via cvt_pk, ds_write_b64 col-major ----
#pragma unroll
    for (int n = 0; n < 4; ++n) {
      float pa0 = exp2f(sA[n][0] - mA[0]), pa1 = exp2f(sA[n][1] - mA[1]);
      float pa2 = exp2f(sA[n][2] - mA[2]), pa3 = exp2f(sA[n][3] - mA[3]);
      float pb0 = exp2f(sB[n][0] - mB[0]), pb1 = exp2f(sB[n][1] - mB[1]);
      float pb2 = exp2f(sB[n][2] - mB[2]), pb3 = exp2f(sB[n][3] - mB[3]);
      if (!diag) {
        pa0 *= colmul; pa1 *= colmul; pa2 *= colmul; pa3 *= colmul;
        pb0 *= colmul; pb1 *= colmul; pb2 *= colmul; pb3 *= colmul;
      }
      lA[0] += pa0; lA[1] += pa1; lA[2] += pa2; lA[3] += pa3;
      lB[0] += pb0; lB[1] += pb1; lB[2] += pb2; lB[3] += pb3;
      u32x2 wa = {cvtpk(pa0, pa1), cvtpk(pa2, pa3)};
      u32x2 wb = {cvtpk(pb0, pb1), cvtpk(pb2, pb3)};
      *(u32x2*)(pwA + n * 512) = wa;
      *(u32x2*)(pwB + n * 512) = wb;
    }
    // ---- read A-frags back via HW transpose ----
    bf16x8 paA[2], paB[2];
    paA[0] = tr_frag(trA);       paA[1] = tr_frag(trA + 512);
    paB[0] = tr_frag(trB);       paB[1] = tr_frag(trB + 512);
    asm volatile("s_waitcnt lgkmcnt(0)" ::: "memory");
    __builtin_amdgcn_sched_barrier(0);
    // ---- PV ----
#pragma unroll
    for (int kk = 0; kk < 2; ++kk)
#pragma unroll
      for (int n = 0; n < 4; ++n) {
        yA[n] = __builtin_amdgcn_mfma_f32_16x16x32_bf16(paA[kk], vf[n][kk], yA[n], 0, 0, 0);
        yB[n] = __builtin_amdgcn_mfma_f32_16x16x32_bf16(paB[kk], vf[n][kk], yB[n], 0, 0, 0);
      }
  };

  // ping-pong over s-tiles with K register prefetch
  LOADK(k0, 0);
  int i = 0;
  for (;;) {
    if (i + 1 <= ndiag) LOADK(k1, (i + 1) * 64);
    BODY(k0, i * 64, i == ndiag);
    if (++i > ndiag) break;
    if (i + 1 <= ndiag) LOADK(k0, (i + 1) * 64);
    BODY(k1, i * 64, i == ndiag);
    if (++i > ndiag) break;
  }

  // ---- epilogue: reduce l partials once, scale, store ----
#pragma unroll
  for (int off = 1; off < 16; off <<= 1)
#pragma unroll
    for (int r = 0; r < 4; ++r) {
      lA[r] += __shfl_xor(lA[r], off, 64);
      lB[r] += __shfl_xor(lB[r], off, 64);
    }
  const int b = bh >> 4, h = bh & 15;
#pragma unroll
  for (int r = 0; r < 4; ++r) {
    const float invA = 1.0f / lA[r], invB = 1.0f / lB[r];
    const int tA = q0 + g * 4 + r;
#pragma unroll
    for (int n = 0; n < 4; ++n) {
      Yb[((size_t)(b * T_SEQ + tA)) * C_DIM + h * HD + n * 16 + fr] = f2bf(yA[n][r] * invA);
      Yb[((size_t)(b * T_SEQ + tA + 16)) * C_DIM + h * HD + n * 16 + fr] = f2bf(yB[n][r] * invB);
    }
  }
}

// ---------- output projection ----------
__global__ __launch_bounds__(256) void k_gemm_out(
    const unsigned short* __restrict__ Yb,
    const unsigned short* __restrict__ Wpt,
    const float* __restrict__ bp,
    float* __restrict__ out)
{
  __shared__ __attribute__((aligned(16))) unsigned short As[128 * 32];
  __shared__ __attribute__((aligned(16))) unsigned short Bs[128 * 32];
  f32x4 acc[4][4];
  const int m0 = blockIdx.y * 128, n0 = blockIdx.x * 128;
  gemm_tile_mainloop<1024>(Yb, Wpt, m0, n0, As, Bs, acc);

  const int lane = threadIdx.x & 63, wave = threadIdx.x >> 6;
  const int wr = wave >> 1, wc = wave & 1;
  const int fr = lane & 15, g = lane >> 4;
#pragma unroll
  for (int ni = 0; ni < 4; ++ni) {
    const int col = n0 + wc * 64 + ni * 16 + fr;
    const float bb = bp[col];
#pragma unroll
    for (int mi = 0; mi < 4; ++mi)
#pragma unroll
      for (int r = 0; r < 4; ++r) {
        const int row = m0 + wr * 64 + mi * 16 + g * 4 + r;
        out[(size_t)row * C_DIM + col] = acc[mi][ni][r] + bb;
      }
  }
}

// ---------- launch ----------
extern "C" void kernel_launch(void* const* d_in, const int* in_sizes, int n_in,
                              void* d_out, int out_size, void* d_ws, size_t ws_size,
                              hipStream_t stream) {
  const float* x  = (const float*)d_in[0];
  const float* Wq = (const float*)d_in[1];
  const float* bq = (const float*)d_in[2];
  const float* Wk = (const float*)d_in[3];
  const float* bk = (const float*)d_in[4];
  const float* Wv = (const float*)d_in[5];
  const float* bv = (const float*)d_in[6];
  const float* Wp = (const float*)d_in[7];
  const float* bp = (const float*)d_in[8];
  float* out = (float*)d_out;

  char* ws = (char*)d_ws;
  unsigned short* Xb   = (unsigned short*)(ws);                             // 8 MB
  unsigned short* Wt   = (unsigned short*)(ws + (8u  << 20));               // 6 MB
  unsigned short* Wpt  = (unsigned short*)(ws + (14u << 20));               // 2 MB
  float*          bqkv = (float*)         (ws + (16u << 20));               // 12 KB
  unsigned short* Qb   = (unsigned short*)(ws + (16u << 20) + (64u << 10)); // 8 MB
  unsigned short* Kb   = (unsigned short*)(ws + (24u << 20) + (64u << 10)); // 8 MB
  unsigned short* Vt   = (unsigned short*)(ws + (32u << 20) + (64u << 10)); // 8 MB
  unsigned short* Yb   = (unsigned short*)(ws + (40u << 20) + (64u << 10)); // 8 MB

  k_cvt_x<<<4096, 256, 0, stream>>>(x, Xb);
  dim3 tb(32, 8);
  k_transpose_w<<<dim3(32, 32), tb, 0, stream>>>(Wq, Wt);
  k_transpose_w<<<dim3(32, 32), tb, 0, stream>>>(Wk, Wt + (1u << 20));
  k_transpose_w<<<dim3(32, 32), tb, 0, stream>>>(Wv, Wt + (2u << 20));
  k_transpose_w<<<dim3(32, 32), tb, 0, stream>>>(Wp, Wpt);
  k_concat_bias<<<12, 256, 0, stream>>>(bq, bk, bv, bqkv);
  k_gemm_qkv<<<dim3(24, 32), 256, 0, stream>>>(Xb, Wt, bqkv, Qb, Kb, Vt);
  k_attn<<<dim3(64, 32), 64, 0, stream>>>(Qb, Kb, Vt, Yb);
  k_gemm_out<<<dim3(8, 32), 256, 0, stream>>>(Yb, Wpt, bp, out);
}